// Round 15
// baseline (168.145 us; speedup 1.0000x reference)
//
#include <hip/hip_runtime.h>
#include <stdint.h>

// KNN K=16 over x (B=2, N=8192, D=64) f32. Output int32 (2,B,N,K): nn_idx, center_idx.
// Pipeline: split_k (bf16 hi split into TILE-PERMUTED layout + norms) -> red_k ->
// tau_p (MFMA min-ladders over 4096-sample) -> tau_m -> filter_k (MFMA filter)
// -> rerank_k (f32 fast path + provable margin check; rare f64 fallback).
// LESSONS LOG:
//  R7/R8: register prefetch spills (425MB/87MB scratch). NO prefetch/unroll.
//  R9/R12: duration tracks fragment-load instruction count; binder = per-instr
//      memory transactions. R13 tile-permute fixed it (contiguous 1KB loads).
//  R11: LDS staging loses to barrier drains. NO staging.
//  R14: rerank barrier/LDS/scalar-load removal = NEUTRAL (latencies TLP-hidden).
//  R15 (this): rerank is f64-VALU-THROUGHPUT-bound (~268M f64 fma + 134M cvt
//      ~ 20-25us). f32 single-round fast path (margin 8e-6*key, lanes 1..16
//      adjacent-gap check provably catches any top-16 membership/order hazard;
//      sum-of-gaps argument) -> hazard or total>64 falls back to R14 f64 loop
//      (reuses register myid; no extra state). ~83us of total is harness
//      workspace poison (2x 256MB fill) — untouchable.
// Bound: |key_approx - key_true| <= 2(n_q E + e_q H), E = max e, H = Nmax + E.
// tau = u16 + 2*slop provably keeps all true top-16 (pigeonhole over 4096-sample).
constexpr int N_    = 8192;
constexpr int D_    = 64;
constexpr int K_    = 16;
constexpr int NQ    = 16384;          // 2*8192
constexpr int MS    = 8;              // m-superblocks per batch (1024 m each)
constexpr int CAPB  = 40;             // survivor cap per (query, superblock)

typedef __attribute__((ext_vector_type(8))) short bf16x8;
typedef __attribute__((ext_vector_type(4))) float f32x4;
typedef __attribute__((ext_vector_type(8))) unsigned short u16x8;

template<int JN>
__device__ __forceinline__ void topk_insertf(float (&key)[JN], float nk) {
    if (nk < key[JN - 1]) {
        bool c[JN];
#pragma unroll
        for (int j = 0; j < JN; ++j) c[j] = nk < key[j];
#pragma unroll
        for (int j = JN - 1; j >= 1; --j)
            key[j] = c[j - 1] ? key[j - 1] : (c[j] ? nk : key[j]);
        key[0] = c[0] ? nk : key[0];
    }
}

__device__ __forceinline__ unsigned short bf16_rne(float f) {
    uint32_t u = __float_as_uint(f);
    return (unsigned short)((u + 0x7FFFu + ((u >> 16) & 1u)) >> 16);   // no NaN in data
}

__device__ __forceinline__ unsigned long long bitonic64(unsigned long long v, int lane) {
#pragma unroll
    for (int k = 2; k <= 64; k <<= 1)
#pragma unroll
        for (int j = k >> 1; j > 0; j >>= 1) {
            unsigned long long o = __shfl_xor(v, j, 64);
            const bool keepmin = (((lane & k) == 0) == ((lane & j) == 0));
            unsigned long long mn = v < o ? v : o;
            unsigned long long mx = v < o ? o : v;
            v = keepmin ? mn : mx;
        }
    return v;
}

// K1: bf16 hi split + true squared norms + residual norms. 16 lanes/row. grid=1024.
// xh written TILE-PERMUTED: elem (row,e) -> (row>>4)*1024 + (e>>3)*128 + (row&15)*8 + (e&7).
__global__ void __launch_bounds__(256) split_k(const float* __restrict__ x,
                                               unsigned short* __restrict__ xh,
                                               float* __restrict__ nrm,
                                               float* __restrict__ eres) {
    const int t = blockIdx.x * 256 + (int)threadIdx.x;    // one float4 per thread
    const int row = t >> 4, seg = t & 15;                 // elements e = seg*4..seg*4+3
    const float4 v = reinterpret_cast<const float4*>(x)[t];
    float f[4] = {v.x, v.y, v.z, v.w};
    unsigned short h[4];
    float sq = 0.f, esq = 0.f;
#pragma unroll
    for (int j = 0; j < 4; ++j) {
        sq = fmaf(f[j], f[j], sq);
        h[j] = bf16_rne(f[j]);
        float hf = __uint_as_float((uint32_t)h[j] << 16);
        float r  = f[j] - hf;
        esq = fmaf(r, r, esq);
    }
    sq  += __shfl_xor(sq, 1, 16);  sq  += __shfl_xor(sq, 2, 16);
    sq  += __shfl_xor(sq, 4, 16);  sq  += __shfl_xor(sq, 8, 16);
    esq += __shfl_xor(esq, 1, 16); esq += __shfl_xor(esq, 2, 16);
    esq += __shfl_xor(esq, 4, 16); esq += __shfl_xor(esq, 8, 16);
    if (seg == 0) { nrm[row] = sq; eres[row] = sqrtf(esq); }
    ushort4 hv = {h[0], h[1], h[2], h[3]};
    const size_t po = (size_t)(row >> 4) * 1024 + (seg >> 1) * 128 + (row & 15) * 8 + (seg & 1) * 4;
    *reinterpret_cast<ushort4*>(xh + po) = hv;
}

// K1b: per-batch maxima: EH[b] = {Nmax, Emax} (inflated for f32 rounding). grid=2.
__global__ void __launch_bounds__(256) red_k(const float* __restrict__ nrm,
                                             const float* __restrict__ eres,
                                             float* __restrict__ EH) {
    __shared__ float mbuf[8];
    const int b = (int)blockIdx.x, tid = (int)threadIdx.x;
    float mn = 0.f, me = 0.f;
    for (int i = tid; i < N_; i += 256) {
        mn = fmaxf(mn, nrm[b * N_ + i]);
        me = fmaxf(me, eres[b * N_ + i]);
    }
#pragma unroll
    for (int s = 1; s < 64; s <<= 1) {
        mn = fmaxf(mn, __shfl_xor(mn, s, 64));
        me = fmaxf(me, __shfl_xor(me, s, 64));
    }
    const int w = tid >> 6;
    if ((tid & 63) == 0) { mbuf[w * 2] = mn; mbuf[w * 2 + 1] = me; }
    __syncthreads();
    if (tid == 0) {
        for (int i = 1; i < 4; ++i) {
            mn = fmaxf(mn, mbuf[i * 2]); me = fmaxf(me, mbuf[i * 2 + 1]);
        }
        EH[b * 2]     = sqrtf(mn) * 1.0002f + 1e-6f;      // Nmax upper bound
        EH[b * 2 + 1] = me * 1.0002f + 1e-7f;             // Emax upper bound
    }
}

// Fragment load from tile-permuted xh: rowblk's 16 rows, elems (half*4+quad)*8..+8
// for lane (quad,l15) = ONE contiguous 1KB block per wave per (half) pair.
__device__ __forceinline__ bf16x8 frag_ld(const unsigned short* __restrict__ xhb,
                                          int rowblk, int half, int quad, int l15) {
    return *(const bf16x8*)(xhb + (size_t)rowblk * 1024 + (half * 4 + quad) * 128 + l15 * 8);
}

// K2a: MFMA tau partials over a 4096-sample (permuted-layout loads).
// Block = 128q x 1024 samples (quarter sh), 16 chunks of 64. grid = 512.
__global__ void __launch_bounds__(256, 4) tau_p(const unsigned short* __restrict__ xh,
                                                const float* __restrict__ nrm,
                                                float* __restrict__ part) {
    __shared__ alignas(16) float nrmS[1024];                // 4 KB sample norms
    const int tid = (int)threadIdx.x;
    const int bid = (int)blockIdx.x;
    const int qt  = bid >> 2, sh = bid & 3;
    const int q0g = qt * 128;
    const int b   = q0g >> 13;                              // uniform (128 | 8192)
    const int q0l = q0g & (N_ - 1);
    const int s0  = sh * 1024;
    const unsigned short* __restrict__ xhb = xh + (size_t)b * N_ * D_;
    const float* __restrict__ nb = nrm + b * N_;
    const int w = tid >> 6, lane = tid & 63;
    const int wq = w >> 1, wm = w & 1;                      // 64q x 32s wave subtile
    const int l15 = lane & 15, quad = lane >> 4;

    *(float4*)(nrmS + tid * 4) = *(const float4*)(nb + s0 + tid * 4);

    bf16x8 Af[2][4];                                        // A frags (contiguous 1KB loads)
#pragma unroll
    for (int half = 0; half < 2; ++half)
#pragma unroll
        for (int tm = 0; tm < 4; ++tm)
            Af[half][tm] = frag_ld(xhb, (q0l >> 4) + wq * 4 + tm, half, quad, l15);
    float lad[16];
#pragma unroll
    for (int j = 0; j < 16; ++j) lad[j] = __builtin_inff();
    __syncthreads();                                        // nrmS visible

    for (int mc = 0; mc < 16; ++mc) {
        bf16x8 Bf[2][2];                                    // contiguous 1KB loads
#pragma unroll
        for (int half = 0; half < 2; ++half)
#pragma unroll
            for (int tn = 0; tn < 2; ++tn)
                Bf[half][tn] = frag_ld(xhb, sh * 64 + mc * 4 + wm * 2 + tn, half, quad, l15);
        f32x4 acc[4][2] = {};
#pragma unroll
        for (int half = 0; half < 2; ++half)
#pragma unroll
            for (int tm = 0; tm < 4; ++tm)
#pragma unroll
                for (int tn = 0; tn < 2; ++tn)
                    acc[tm][tn] = __builtin_amdgcn_mfma_f32_16x16x32_bf16(Af[half][tm], Bf[half][tn], acc[tm][tn], 0, 0, 0);
        // epilogue: C/D col=lane&15 (sample), row=quad*4+reg (q); depth-1 min
#pragma unroll
        for (int tn = 0; tn < 2; ++tn) {
            const float nm = nrmS[mc * 64 + wm * 32 + tn * 16 + l15];
#pragma unroll
            for (int tm = 0; tm < 4; ++tm)
#pragma unroll
                for (int reg = 0; reg < 4; ++reg)
                    lad[tm * 4 + reg] = fminf(lad[tm * 4 + reg],
                                              fmaf(-2.f, acc[tm][tn][reg], nm));
        }
    }
    // part[q][128]: offset = sh*32 + wm*16 + l15
#pragma unroll
    for (int tm = 0; tm < 4; ++tm)
#pragma unroll
        for (int reg = 0; reg < 4; ++reg) {
            const int q = q0g + wq * 64 + tm * 16 + quad * 4 + reg;
            part[(size_t)q * 128 + sh * 32 + wm * 16 + l15] = lad[tm * 4 + reg];
        }
}

// K2b: merge 128 partials/query -> tau with provable slop. grid = NQ/64 = 256.
__global__ void __launch_bounds__(64) tau_m(const float* __restrict__ part,
                                            const float* __restrict__ nrm,
                                            const float* __restrict__ eres,
                                            const float* __restrict__ EH,
                                            float* __restrict__ tau) {
    const int q = blockIdx.x * 64 + (int)threadIdx.x;
    const int b = q >> 13;
    const float4* p = reinterpret_cast<const float4*>(part + (size_t)q * 128);
    float key[K_];
#pragma unroll
    for (int j = 0; j < K_; ++j) key[j] = __builtin_inff();
    for (int i = 0; i < 32; ++i) {
        float4 v = p[i];
        topk_insertf<K_>(key, v.x); topk_insertf<K_>(key, v.y);
        topk_insertf<K_>(key, v.z); topk_insertf<K_>(key, v.w);
    }
    const float Nmax = EH[b * 2], Emax = EH[b * 2 + 1];
    const float H = Nmax + Emax;                            // >= max ||xh_m||
    const float nq = sqrtf(nrm[q]) * 1.0001f, eq = eres[q];
    tau[q] = key[15] + 4.f * (nq * Emax + eq * H) + 6e-3f;  // 2*s_q + f32 fudge
}

// K3: MFMA filter, BARRIER-FREE streaming, 256q x 1024m blocks, permuted-layout
// fragment loads (contiguous 1KB per instr). 512 threads = 8 waves (4 wq x 2 wm);
// per-wave tile Af[2][4]/acc[4][2]. grid = 512 (2/CU).
__global__ void __launch_bounds__(512, 4) filter_k(const unsigned short* __restrict__ xh,
                                                   const float* __restrict__ nrm,
                                                   const float* __restrict__ tau,
                                                   unsigned short* __restrict__ cnt_pb,
                                                   unsigned short* __restrict__ buf2) {
    __shared__ alignas(16) float nrmS[1024];                // 4 KB superblock norms
    __shared__ unsigned short lists[256 * CAPB];            // 20 KB
    __shared__ unsigned int cntL[256];
    const int tid = (int)threadIdx.x;
    const int bid = (int)blockIdx.x;
    const int b  = bid >> 8;
    const int qt = (bid >> 3) & 31;
    const int ms = bid & 7;
    const int q0 = qt * 256;
    const unsigned short* __restrict__ xhb = xh + (size_t)b * N_ * D_;
    const float* __restrict__ nb = nrm + b * N_;
    const int w = tid >> 6, lane = tid & 63;
    const int wq = w >> 1, wm = w & 1;                      // 64q x 32m wave subtile
    const int l15 = lane & 15, quad = lane >> 4;

    if (tid < 256) {
        *(float4*)(nrmS + tid * 4) = *(const float4*)(nb + ms * 1024 + tid * 4);
        cntL[tid] = 0;
    }

    bf16x8 Af[2][4];                                        // A frags (contiguous 1KB loads)
#pragma unroll
    for (int half = 0; half < 2; ++half)
#pragma unroll
        for (int tm = 0; tm < 4; ++tm)
            Af[half][tm] = frag_ld(xhb, qt * 16 + wq * 4 + tm, half, quad, l15);
    f32x4 t4v[4];
#pragma unroll
    for (int tm = 0; tm < 4; ++tm)
        t4v[tm] = *(const f32x4*)(tau + (b << 13) + q0 + wq * 64 + tm * 16 + quad * 4);
    __syncthreads();                                        // nrmS + cntL visible

    for (int mc = 0; mc < 16; ++mc) {
        bf16x8 Bf[2][2];                                    // contiguous 1KB loads
#pragma unroll
        for (int half = 0; half < 2; ++half)
#pragma unroll
            for (int tn = 0; tn < 2; ++tn)
                Bf[half][tn] = frag_ld(xhb, ms * 64 + mc * 4 + wm * 2 + tn, half, quad, l15);
        f32x4 acc[4][2] = {};
#pragma unroll
        for (int half = 0; half < 2; ++half)
#pragma unroll
            for (int tm = 0; tm < 4; ++tm)
#pragma unroll
                for (int tn = 0; tn < 2; ++tn)
                    acc[tm][tn] = __builtin_amdgcn_mfma_f32_16x16x32_bf16(Af[half][tm], Bf[half][tn], acc[tm][tn], 0, 0, 0);
        // epilogue: C/D col=lane&15 (m), row=quad*4+reg (q); accept key <= tau
#pragma unroll
        for (int tn = 0; tn < 2; ++tn) {
            const int mloc = mc * 64 + wm * 32 + tn * 16 + l15;
            const float nm = nrmS[mloc];
            const unsigned short mid = (unsigned short)(ms * 1024 + mloc);
#pragma unroll
            for (int tm = 0; tm < 4; ++tm)
#pragma unroll
                for (int reg = 0; reg < 4; ++reg) {
                    float keyf = fmaf(-2.f, acc[tm][tn][reg], nm);
                    if (keyf <= t4v[tm][reg]) {             // rare (~0.4%)
                        int ql = wq * 64 + tm * 16 + quad * 4 + reg;
                        unsigned pos = atomicAdd(&cntL[ql], 1u);    // LDS atomic
                        if (pos < CAPB) lists[ql * CAPB + pos] = mid;
                    }
                }
        }
    }
    __syncthreads();                                        // all waves' accepts visible
    if (tid < 256) {                                        // flush to fixed slots
        const int q = (b << 13) + q0 + tid;
        unsigned cn = cntL[tid]; cn = cn < CAPB ? cn : CAPB;
        cnt_pb[(size_t)q * MS + ms] = (unsigned short)cn;
        unsigned short* dst = buf2 + ((size_t)q * MS + ms) * CAPB;
        for (unsigned i = 0; i < cn; ++i) dst[i] = lists[tid * CAPB + i];
    }
}

// K4: rerank, wave-per-query. F32 FAST PATH (R15): single round (total<=64,
// ~always), f32 distance (rel err <= ~2.2e-6), key=(f32bits<<32)|id, one
// bitonic sort, margin check on lanes 1..16 adjacent gaps (8e-6*key margin;
// sum-of-gaps argument covers all membership/order hazards; NaN empty lanes
// compare false). Hazard or total>64 -> proven R14 f64 loop (reuses register
// myid; ids LDS only populated when total>64). block 256 = 4 waves; grid 4096.
__global__ void __launch_bounds__(256) rerank_k(const float* __restrict__ x,
                                                const unsigned short* __restrict__ cnt_pb,
                                                const unsigned short* __restrict__ buf2,
                                                int* __restrict__ out) {
    __shared__ float Qs[4 * 64];                           // 1 KB query rows (wave-private)
    __shared__ unsigned short ids[4 * MS * CAPB];          // 2.5 KB survivors (wave-private)
    const int tid = (int)threadIdx.x;
    const int w = tid >> 6, lane = tid & 63;
    const int q = blockIdx.x * 4 + w;
    const int b = q >> 13, n = q & (N_ - 1);
    const float* __restrict__ xb = x + (size_t)b * N_ * D_;
    Qs[w * 64 + lane] = xb[(size_t)n * D_ + lane];

    const u16x8 cv = *reinterpret_cast<const u16x8*>(cnt_pb + (size_t)q * MS);  // 16B, aligned
    int off[MS + 1]; off[0] = 0;                           // all lanes compute same
#pragma unroll
    for (int ms = 0; ms < MS; ++ms) {
        int c = (int)cv[ms]; c = c < CAPB ? c : CAPB;
        off[ms + 1] = off[ms] + c;
    }
    const int total = off[MS];                             // >= 16 guaranteed (true top-16 pass)
    int myid = 0;                                          // register fast path (idx == lane)
    for (int idx = lane; idx < total; idx += 64) {         // compact ids
        int ms = 0;
#pragma unroll
        for (int t = 1; t < MS; ++t) ms += (idx >= off[t]) ? 1 : 0;
        const int id = (int)buf2[((size_t)q * MS + ms) * CAPB + (idx - off[ms])];
        if (idx == lane) myid = id;
        if (total > 64) ids[(w * MS) * CAPB + idx] = (unsigned short)id;  // refill only
    }
    // no barrier: all LDS traffic is same-wave.

    unsigned long long v;
    bool slow = total > 64;
    if (!slow) {
        // ---------------- f32 fast path ----------------
        unsigned long long nk = ~0ull;
        if (lane < total) {
            const float* __restrict__ crow = xb + (size_t)myid * D_;
            float a0 = 0.f, a1 = 0.f, a2 = 0.f, a3 = 0.f;
#pragma unroll
            for (int j = 0; j < 16; ++j) {
                const float4 c  = *(const float4*)(crow + j * 4);        // per-lane gather
                const float4 qv = *(const float4*)(Qs + w * 64 + j * 4); // uniform -> broadcast
                float d0 = qv.x - c.x; a0 = fmaf(d0, d0, a0);
                float d1 = qv.y - c.y; a1 = fmaf(d1, d1, a1);
                float d2 = qv.z - c.z; a2 = fmaf(d2, d2, a2);
                float d3 = qv.w - c.w; a3 = fmaf(d3, d3, a3);
            }
            float s = (a0 + a1) + (a2 + a3);               // >= 0, finite
            nk = ((unsigned long long)__float_as_uint(s) << 32) | (unsigned)myid;
        }
        v = bitonic64(nk, lane);
        // hazard check: lanes 1..16 adjacent gaps (covers order within top-16
        // AND the 15/16 membership boundary; NaN empty lanes compare false).
        const unsigned long long pv = __shfl_up(v, 1, 64);
        const float pk = __uint_as_float((unsigned)(pv >> 32));
        const float mk = __uint_as_float((unsigned)(v  >> 32));
        const bool amb = (lane >= 1 && lane <= 16) &&
                         ((mk - pk) <= fmaf(mk, 8e-6f, 1e-12f));
        slow = __ballot(amb) != 0ull;
        if (!slow) {                                       // wave-uniform exit
            if (lane < K_) {
                out[(size_t)q * K_ + lane]                   = (int)(v & 0xFFFFFFFFull);
                out[(size_t)NQ * K_ + (size_t)q * K_ + lane] = n;
            }
            return;
        }
    }
    // ---------------- exact f64 path (rare) ----------------
    v = ~0ull;
    int consumed = 0;
    bool first = true;
    while (first || consumed < total) {
        const int myIdx = first ? lane : consumed + lane - 16;
        const bool take = (first || lane >= 16) && myIdx < total;
        unsigned long long nk = ~0ull;
        if (take) {
            const int id = first ? myid : (int)ids[(w * MS) * CAPB + myIdx];
            const float* __restrict__ crow = xb + (size_t)id * D_;
            double a0 = 0.0, a1 = 0.0, a2 = 0.0, a3 = 0.0;
#pragma unroll
            for (int j = 0; j < 16; ++j) {
                const float4 c  = *(const float4*)(crow + j * 4);
                const float4 qv = *(const float4*)(Qs + w * 64 + j * 4);
                double d0 = (double)qv.x - (double)c.x; a0 = fma(d0, d0, a0);
                double d1 = (double)qv.y - (double)c.y; a1 = fma(d1, d1, a1);
                double d2 = (double)qv.z - (double)c.z; a2 = fma(d2, d2, a2);
                double d3 = (double)qv.w - (double)c.w; a3 = fma(d3, d3, a3);
            }
            double s = (a0 + a1) + (a2 + a3);
            // s >= 0 -> f64 bits order-preserving; low 13 mantissa bits carry the id.
            nk = ((unsigned long long)__double_as_longlong(s) & ~0x1FFFull) | (unsigned)id;
        }
        if (first || lane >= 16) v = nk;                   // lanes 0-15 keep running top-16
        v = bitonic64(v, lane);
        consumed += first ? 64 : 48;
        first = false;
    }
    if (lane < K_) {
        out[(size_t)q * K_ + lane]                   = (int)(v & 0x1FFFull);  // nn_idx
        out[(size_t)NQ * K_ + (size_t)q * K_ + lane] = n;                     // center_idx
    }
}

extern "C" void kernel_launch(void* const* d_in, const int* in_sizes, int n_in,
                              void* d_out, int out_size, void* d_ws, size_t ws_size,
                              hipStream_t stream) {
    const float* x = (const float*)d_in[0];
    int* out = (int*)d_out;
    char* ws = (char*)d_ws;
    float*          nrm    = (float*)ws;                          //  64 KB @ 0
    float*          tau    = (float*)(ws + (64 << 10));           //  64 KB
    float*          eres   = (float*)(ws + (128 << 10));          //  64 KB
    float*          EH     = (float*)(ws + (192 << 10));          //  16 B
    unsigned short* cnt_pb = (unsigned short*)(ws + (256 << 10)); // 256 KB
    unsigned short* xh     = (unsigned short*)(ws + (1 << 20));   //   2 MB (tile-permuted)
    unsigned short* buf2   = (unsigned short*)(ws + (5 << 20));   // 10.5 MB (16384*8*40*2)
    float*          part   = (float*)(ws + (5 << 20));            //   8 MB, ALIASES buf2:
    // part is written by tau_p and fully consumed by tau_m BEFORE filter_k writes buf2.

    hipLaunchKernelGGL(split_k,  dim3(1024), dim3(256), 0, stream, x, xh, nrm, eres);
    hipLaunchKernelGGL(red_k,    dim3(2),    dim3(256), 0, stream, nrm, eres, EH);
    hipLaunchKernelGGL(tau_p,    dim3(512),  dim3(256), 0, stream, xh, nrm, part);
    hipLaunchKernelGGL(tau_m,    dim3(256),  dim3(64),  0, stream, part, nrm, eres, EH, tau);
    hipLaunchKernelGGL(filter_k, dim3(512),  dim3(512), 0, stream, xh, nrm, tau, cnt_pb, buf2);
    hipLaunchKernelGGL(rerank_k, dim3(4096), dim3(256), 0, stream, x, cnt_pb, buf2, out);
}

// Round 16
// 164.329 us; speedup vs baseline: 1.0232x; 1.0232x over previous
//
#include <hip/hip_runtime.h>
#include <stdint.h>

// KNN K=16 over x (B=2, N=8192, D=64) f32. Output int32 (2,B,N,K): nn_idx, center_idx.
// Pipeline: split_k (bf16 hi split into TILE-PERMUTED layout + norms) -> red_k ->
// tau_p (MFMA min-ladders over 4096-sample) -> tau_m -> filter_k (MFMA filter,
// 256q x 1024m blocks, barrier-free streaming) -> rerank_k (exact f64).
// LESSONS LOG:
//  R7/R8: register prefetch spills (425MB/87MB scratch). NO prefetch/unroll.
//  R9/R12 scaling law: duration tracks fragment-load INSTRUCTION count; binder
//      was per-instruction memory transactions. R13 tile-permute fixed it.
//  R11: LDS staging loses to barrier drains. NO staging.
//  R13: TILE-PERMUTED xh [row>>4][e>>3][row&15][e&7] -> contiguous 1KB fragment
//      loads. filter_k 44->~29us, total 181->165.6. SHIPPED.
//  R14: rerank de-serialization (no barrier, reg-resident single-round id,
//      ushort8 count load) = NEUTRAL (latencies TLP-hidden) but kept (cleaner).
//      BEST MEASURED: 164.8 us.
//  R15: f32 fast-path rerank = +3.4us REGRESSION -> rerank is GATHER-LATENCY
//      bound (33 scattered 256B L2 row reads/query), not f64-VALU bound.
//      REVERTED here to exact R14 form. ~83us of total is harness workspace
//      poison (2x 256MB fill) — untouchable floor.
// Bound: |key_approx - key_true| <= 2(n_q E + e_q H), E = max e, H = Nmax + E.
// tau = u16 + 2*slop provably keeps all true top-16 (pigeonhole over 4096-sample).
constexpr int N_    = 8192;
constexpr int D_    = 64;
constexpr int K_    = 16;
constexpr int NQ    = 16384;          // 2*8192
constexpr int MS    = 8;              // m-superblocks per batch (1024 m each)
constexpr int CAPB  = 40;             // survivor cap per (query, superblock)

typedef __attribute__((ext_vector_type(8))) short bf16x8;
typedef __attribute__((ext_vector_type(4))) float f32x4;
typedef __attribute__((ext_vector_type(8))) unsigned short u16x8;

template<int JN>
__device__ __forceinline__ void topk_insertf(float (&key)[JN], float nk) {
    if (nk < key[JN - 1]) {
        bool c[JN];
#pragma unroll
        for (int j = 0; j < JN; ++j) c[j] = nk < key[j];
#pragma unroll
        for (int j = JN - 1; j >= 1; --j)
            key[j] = c[j - 1] ? key[j - 1] : (c[j] ? nk : key[j]);
        key[0] = c[0] ? nk : key[0];
    }
}

__device__ __forceinline__ unsigned short bf16_rne(float f) {
    uint32_t u = __float_as_uint(f);
    return (unsigned short)((u + 0x7FFFu + ((u >> 16) & 1u)) >> 16);   // no NaN in data
}

// K1: bf16 hi split + true squared norms + residual norms. 16 lanes/row. grid=1024.
// xh written TILE-PERMUTED: elem (row,e) -> (row>>4)*1024 + (e>>3)*128 + (row&15)*8 + (e&7).
// (row>>4 is GLOBAL: batch folds in since 512*1024 = 8192*64.)
__global__ void __launch_bounds__(256) split_k(const float* __restrict__ x,
                                               unsigned short* __restrict__ xh,
                                               float* __restrict__ nrm,
                                               float* __restrict__ eres) {
    const int t = blockIdx.x * 256 + (int)threadIdx.x;    // one float4 per thread
    const int row = t >> 4, seg = t & 15;                 // elements e = seg*4..seg*4+3
    const float4 v = reinterpret_cast<const float4*>(x)[t];
    float f[4] = {v.x, v.y, v.z, v.w};
    unsigned short h[4];
    float sq = 0.f, esq = 0.f;
#pragma unroll
    for (int j = 0; j < 4; ++j) {
        sq = fmaf(f[j], f[j], sq);
        h[j] = bf16_rne(f[j]);
        float hf = __uint_as_float((uint32_t)h[j] << 16);
        float r  = f[j] - hf;
        esq = fmaf(r, r, esq);
    }
    sq  += __shfl_xor(sq, 1, 16);  sq  += __shfl_xor(sq, 2, 16);
    sq  += __shfl_xor(sq, 4, 16);  sq  += __shfl_xor(sq, 8, 16);
    esq += __shfl_xor(esq, 1, 16); esq += __shfl_xor(esq, 2, 16);
    esq += __shfl_xor(esq, 4, 16); esq += __shfl_xor(esq, 8, 16);
    if (seg == 0) { nrm[row] = sq; eres[row] = sqrtf(esq); }
    ushort4 hv = {h[0], h[1], h[2], h[3]};
    const size_t po = (size_t)(row >> 4) * 1024 + (seg >> 1) * 128 + (row & 15) * 8 + (seg & 1) * 4;
    *reinterpret_cast<ushort4*>(xh + po) = hv;
}

// K1b: per-batch maxima: EH[b] = {Nmax, Emax} (inflated for f32 rounding). grid=2.
__global__ void __launch_bounds__(256) red_k(const float* __restrict__ nrm,
                                             const float* __restrict__ eres,
                                             float* __restrict__ EH) {
    __shared__ float mbuf[8];
    const int b = (int)blockIdx.x, tid = (int)threadIdx.x;
    float mn = 0.f, me = 0.f;
    for (int i = tid; i < N_; i += 256) {
        mn = fmaxf(mn, nrm[b * N_ + i]);
        me = fmaxf(me, eres[b * N_ + i]);
    }
#pragma unroll
    for (int s = 1; s < 64; s <<= 1) {
        mn = fmaxf(mn, __shfl_xor(mn, s, 64));
        me = fmaxf(me, __shfl_xor(me, s, 64));
    }
    const int w = tid >> 6;
    if ((tid & 63) == 0) { mbuf[w * 2] = mn; mbuf[w * 2 + 1] = me; }
    __syncthreads();
    if (tid == 0) {
        for (int i = 1; i < 4; ++i) {
            mn = fmaxf(mn, mbuf[i * 2]); me = fmaxf(me, mbuf[i * 2 + 1]);
        }
        EH[b * 2]     = sqrtf(mn) * 1.0002f + 1e-6f;      // Nmax upper bound
        EH[b * 2 + 1] = me * 1.0002f + 1e-7f;             // Emax upper bound
    }
}

// Fragment load from tile-permuted xh: rowblk's 16 rows, elems (half*4+quad)*8..+8
// for lane (quad,l15) = ONE contiguous 1KB block per wave per (half) pair.
__device__ __forceinline__ bf16x8 frag_ld(const unsigned short* __restrict__ xhb,
                                          int rowblk, int half, int quad, int l15) {
    return *(const bf16x8*)(xhb + (size_t)rowblk * 1024 + (half * 4 + quad) * 128 + l15 * 8);
}

// K2a: MFMA tau partials over a 4096-sample (permuted-layout loads).
// Block = 128q x 1024 samples (quarter sh), 16 chunks of 64. grid = 512.
__global__ void __launch_bounds__(256, 4) tau_p(const unsigned short* __restrict__ xh,
                                                const float* __restrict__ nrm,
                                                float* __restrict__ part) {
    __shared__ alignas(16) float nrmS[1024];                // 4 KB sample norms
    const int tid = (int)threadIdx.x;
    const int bid = (int)blockIdx.x;
    const int qt  = bid >> 2, sh = bid & 3;
    const int q0g = qt * 128;
    const int b   = q0g >> 13;                              // uniform (128 | 8192)
    const int q0l = q0g & (N_ - 1);
    const int s0  = sh * 1024;
    const unsigned short* __restrict__ xhb = xh + (size_t)b * N_ * D_;
    const float* __restrict__ nb = nrm + b * N_;
    const int w = tid >> 6, lane = tid & 63;
    const int wq = w >> 1, wm = w & 1;                      // 64q x 32s wave subtile
    const int l15 = lane & 15, quad = lane >> 4;

    *(float4*)(nrmS + tid * 4) = *(const float4*)(nb + s0 + tid * 4);

    bf16x8 Af[2][4];                                        // A frags (contiguous 1KB loads)
#pragma unroll
    for (int half = 0; half < 2; ++half)
#pragma unroll
        for (int tm = 0; tm < 4; ++tm)
            Af[half][tm] = frag_ld(xhb, (q0l >> 4) + wq * 4 + tm, half, quad, l15);
    float lad[16];
#pragma unroll
    for (int j = 0; j < 16; ++j) lad[j] = __builtin_inff();
    __syncthreads();                                        // nrmS visible

    for (int mc = 0; mc < 16; ++mc) {
        bf16x8 Bf[2][2];                                    // contiguous 1KB loads
#pragma unroll
        for (int half = 0; half < 2; ++half)
#pragma unroll
            for (int tn = 0; tn < 2; ++tn)
                Bf[half][tn] = frag_ld(xhb, sh * 64 + mc * 4 + wm * 2 + tn, half, quad, l15);
        f32x4 acc[4][2] = {};
#pragma unroll
        for (int half = 0; half < 2; ++half)
#pragma unroll
            for (int tm = 0; tm < 4; ++tm)
#pragma unroll
                for (int tn = 0; tn < 2; ++tn)
                    acc[tm][tn] = __builtin_amdgcn_mfma_f32_16x16x32_bf16(Af[half][tm], Bf[half][tn], acc[tm][tn], 0, 0, 0);
        // epilogue: C/D col=lane&15 (sample), row=quad*4+reg (q); depth-1 min
#pragma unroll
        for (int tn = 0; tn < 2; ++tn) {
            const float nm = nrmS[mc * 64 + wm * 32 + tn * 16 + l15];
#pragma unroll
            for (int tm = 0; tm < 4; ++tm)
#pragma unroll
                for (int reg = 0; reg < 4; ++reg)
                    lad[tm * 4 + reg] = fminf(lad[tm * 4 + reg],
                                              fmaf(-2.f, acc[tm][tn][reg], nm));
        }
    }
    // part[q][128]: offset = sh*32 + wm*16 + l15
#pragma unroll
    for (int tm = 0; tm < 4; ++tm)
#pragma unroll
        for (int reg = 0; reg < 4; ++reg) {
            const int q = q0g + wq * 64 + tm * 16 + quad * 4 + reg;
            part[(size_t)q * 128 + sh * 32 + wm * 16 + l15] = lad[tm * 4 + reg];
        }
}

// K2b: merge 128 partials/query -> tau with provable slop. grid = NQ/64 = 256.
__global__ void __launch_bounds__(64) tau_m(const float* __restrict__ part,
                                            const float* __restrict__ nrm,
                                            const float* __restrict__ eres,
                                            const float* __restrict__ EH,
                                            float* __restrict__ tau) {
    const int q = blockIdx.x * 64 + (int)threadIdx.x;
    const int b = q >> 13;
    const float4* p = reinterpret_cast<const float4*>(part + (size_t)q * 128);
    float key[K_];
#pragma unroll
    for (int j = 0; j < K_; ++j) key[j] = __builtin_inff();
    for (int i = 0; i < 32; ++i) {
        float4 v = p[i];
        topk_insertf<K_>(key, v.x); topk_insertf<K_>(key, v.y);
        topk_insertf<K_>(key, v.z); topk_insertf<K_>(key, v.w);
    }
    const float Nmax = EH[b * 2], Emax = EH[b * 2 + 1];
    const float H = Nmax + Emax;                            // >= max ||xh_m||
    const float nq = sqrtf(nrm[q]) * 1.0001f, eq = eres[q];
    tau[q] = key[15] + 4.f * (nq * Emax + eq * H) + 6e-3f;  // 2*s_q + f32 fudge
}

// K3: MFMA filter, BARRIER-FREE streaming, 256q x 1024m blocks, permuted-layout
// fragment loads (contiguous 1KB per instr). 512 threads = 8 waves (4 wq x 2 wm);
// per-wave tile Af[2][4]/acc[4][2]. grid = 512 (2/CU).
__global__ void __launch_bounds__(512, 4) filter_k(const unsigned short* __restrict__ xh,
                                                   const float* __restrict__ nrm,
                                                   const float* __restrict__ tau,
                                                   unsigned short* __restrict__ cnt_pb,
                                                   unsigned short* __restrict__ buf2) {
    __shared__ alignas(16) float nrmS[1024];                // 4 KB superblock norms
    __shared__ unsigned short lists[256 * CAPB];            // 20 KB
    __shared__ unsigned int cntL[256];
    const int tid = (int)threadIdx.x;
    const int bid = (int)blockIdx.x;
    const int b  = bid >> 8;
    const int qt = (bid >> 3) & 31;
    const int ms = bid & 7;
    const int q0 = qt * 256;
    const unsigned short* __restrict__ xhb = xh + (size_t)b * N_ * D_;
    const float* __restrict__ nb = nrm + b * N_;
    const int w = tid >> 6, lane = tid & 63;
    const int wq = w >> 1, wm = w & 1;                      // 64q x 32m wave subtile
    const int l15 = lane & 15, quad = lane >> 4;

    if (tid < 256) {
        *(float4*)(nrmS + tid * 4) = *(const float4*)(nb + ms * 1024 + tid * 4);
        cntL[tid] = 0;
    }

    bf16x8 Af[2][4];                                        // A frags (contiguous 1KB loads)
#pragma unroll
    for (int half = 0; half < 2; ++half)
#pragma unroll
        for (int tm = 0; tm < 4; ++tm)
            Af[half][tm] = frag_ld(xhb, qt * 16 + wq * 4 + tm, half, quad, l15);
    f32x4 t4v[4];
#pragma unroll
    for (int tm = 0; tm < 4; ++tm)
        t4v[tm] = *(const f32x4*)(tau + (b << 13) + q0 + wq * 64 + tm * 16 + quad * 4);
    __syncthreads();                                        // nrmS + cntL visible

    for (int mc = 0; mc < 16; ++mc) {
        bf16x8 Bf[2][2];                                    // contiguous 1KB loads
#pragma unroll
        for (int half = 0; half < 2; ++half)
#pragma unroll
            for (int tn = 0; tn < 2; ++tn)
                Bf[half][tn] = frag_ld(xhb, ms * 64 + mc * 4 + wm * 2 + tn, half, quad, l15);
        f32x4 acc[4][2] = {};
#pragma unroll
        for (int half = 0; half < 2; ++half)
#pragma unroll
            for (int tm = 0; tm < 4; ++tm)
#pragma unroll
                for (int tn = 0; tn < 2; ++tn)
                    acc[tm][tn] = __builtin_amdgcn_mfma_f32_16x16x32_bf16(Af[half][tm], Bf[half][tn], acc[tm][tn], 0, 0, 0);
        // epilogue: C/D col=lane&15 (m), row=quad*4+reg (q); accept key <= tau
#pragma unroll
        for (int tn = 0; tn < 2; ++tn) {
            const int mloc = mc * 64 + wm * 32 + tn * 16 + l15;
            const float nm = nrmS[mloc];
            const unsigned short mid = (unsigned short)(ms * 1024 + mloc);
#pragma unroll
            for (int tm = 0; tm < 4; ++tm)
#pragma unroll
                for (int reg = 0; reg < 4; ++reg) {
                    float keyf = fmaf(-2.f, acc[tm][tn][reg], nm);
                    if (keyf <= t4v[tm][reg]) {             // rare (~0.4%)
                        int ql = wq * 64 + tm * 16 + quad * 4 + reg;
                        unsigned pos = atomicAdd(&cntL[ql], 1u);    // LDS atomic
                        if (pos < CAPB) lists[ql * CAPB + pos] = mid;
                    }
                }
        }
    }
    __syncthreads();                                        // all waves' accepts visible
    if (tid < 256) {                                        // flush to fixed slots
        const int q = (b << 13) + q0 + tid;
        unsigned cn = cntL[tid]; cn = cn < CAPB ? cn : CAPB;
        cnt_pb[(size_t)q * MS + ms] = (unsigned short)cn;
        unsigned short* dst = buf2 + ((size_t)q * MS + ms) * CAPB;
        for (unsigned i = 0; i < cn; ++i) dst[i] = lists[tid * CAPB + i];
    }
}

// K4: exact f64 rerank, wave-per-query, DE-SERIALIZED (R14 best-measured form):
//  - NO __syncthreads (Qs/ids segments are wave-private; wave-internal LDS
//    ordering is HW/compiler-guaranteed).
//  - single-round fast path: lane's candidate id stays in a REGISTER (idx==lane
//    during compaction); ids LDS written only when total > 64 (wave-uniform).
//  - cnt_pb read as ONE aligned ushort8 (16 B) instead of 8 scalar loads.
// block 256 = 4 waves = 4 queries; grid = NQ/4 = 4096.
__global__ void __launch_bounds__(256) rerank_k(const float* __restrict__ x,
                                                const unsigned short* __restrict__ cnt_pb,
                                                const unsigned short* __restrict__ buf2,
                                                int* __restrict__ out) {
    __shared__ float Qs[4 * 64];                           // 1 KB query rows (wave-private)
    __shared__ unsigned short ids[4 * MS * CAPB];          // 2.5 KB survivors (wave-private)
    const int tid = (int)threadIdx.x;
    const int w = tid >> 6, lane = tid & 63;
    const int q = blockIdx.x * 4 + w;
    const int b = q >> 13, n = q & (N_ - 1);
    const float* __restrict__ xb = x + (size_t)b * N_ * D_;
    Qs[w * 64 + lane] = xb[(size_t)n * D_ + lane];

    const u16x8 cv = *reinterpret_cast<const u16x8*>(cnt_pb + (size_t)q * MS);  // 16B, aligned
    int off[MS + 1]; off[0] = 0;                           // all lanes compute same
#pragma unroll
    for (int ms = 0; ms < MS; ++ms) {
        int c = (int)cv[ms]; c = c < CAPB ? c : CAPB;
        off[ms + 1] = off[ms] + c;
    }
    const int total = off[MS];                             // >= 16 guaranteed (true top-16 pass)
    int myid = 0;                                          // register fast path (idx == lane)
    for (int idx = lane; idx < total; idx += 64) {         // compact ids
        int ms = 0;
#pragma unroll
        for (int t = 1; t < MS; ++t) ms += (idx >= off[t]) ? 1 : 0;
        const int id = (int)buf2[((size_t)q * MS + ms) * CAPB + (idx - off[ms])];
        if (idx == lane) myid = id;
        if (total > 64) ids[(w * MS) * CAPB + idx] = (unsigned short)id;  // refill only
    }
    // no barrier: all LDS traffic above is same-wave; refill reads below are same-wave.

    unsigned long long v = ~0ull;
    int consumed = 0;
    bool first = true;
    while (first || consumed < total) {
        const int myIdx = first ? lane : consumed + lane - 16;
        const bool take = (first || lane >= 16) && myIdx < total;
        unsigned long long nk = ~0ull;
        if (take) {
            const int id = first ? myid : (int)ids[(w * MS) * CAPB + myIdx];
            const float* __restrict__ crow = xb + (size_t)id * D_;
            double a0 = 0.0, a1 = 0.0, a2 = 0.0, a3 = 0.0;
#pragma unroll
            for (int j = 0; j < 16; ++j) {
                const float4 c  = *(const float4*)(crow + j * 4);        // per-lane gather
                const float4 qv = *(const float4*)(Qs + w * 64 + j * 4); // uniform -> broadcast
                double d0 = (double)qv.x - (double)c.x; a0 = fma(d0, d0, a0);
                double d1 = (double)qv.y - (double)c.y; a1 = fma(d1, d1, a1);
                double d2 = (double)qv.z - (double)c.z; a2 = fma(d2, d2, a2);
                double d3 = (double)qv.w - (double)c.w; a3 = fma(d3, d3, a3);
            }
            double s = (a0 + a1) + (a2 + a3);
            // s >= 0 -> f64 bits order-preserving; low 13 mantissa bits carry the id
            // for exact (dist, id) lexicographic compare (ties -> lower id).
            nk = ((unsigned long long)__double_as_longlong(s) & ~0x1FFFull) | (unsigned)id;
        }
        if (first || lane >= 16) v = nk;                   // lanes 0-15 keep running top-16
        // 64-lane bitonic sort ascending (21 steps)
#pragma unroll
        for (int k = 2; k <= 64; k <<= 1)
#pragma unroll
            for (int j = k >> 1; j > 0; j >>= 1) {
                unsigned long long o = __shfl_xor(v, j, 64);
                const bool keepmin = (((lane & k) == 0) == ((lane & j) == 0));
                unsigned long long mn = v < o ? v : o;
                unsigned long long mx = v < o ? o : v;
                v = keepmin ? mn : mx;
            }
        consumed += first ? 64 : 48;
        first = false;
    }
    if (lane < K_) {
        out[(size_t)q * K_ + lane]                   = (int)(v & 0x1FFFull);  // nn_idx
        out[(size_t)NQ * K_ + (size_t)q * K_ + lane] = n;                     // center_idx
    }
}

extern "C" void kernel_launch(void* const* d_in, const int* in_sizes, int n_in,
                              void* d_out, int out_size, void* d_ws, size_t ws_size,
                              hipStream_t stream) {
    const float* x = (const float*)d_in[0];
    int* out = (int*)d_out;
    char* ws = (char*)d_ws;
    float*          nrm    = (float*)ws;                          //  64 KB @ 0
    float*          tau    = (float*)(ws + (64 << 10));           //  64 KB
    float*          eres   = (float*)(ws + (128 << 10));          //  64 KB
    float*          EH     = (float*)(ws + (192 << 10));          //  16 B
    unsigned short* cnt_pb = (unsigned short*)(ws + (256 << 10)); // 256 KB
    unsigned short* xh     = (unsigned short*)(ws + (1 << 20));   //   2 MB (tile-permuted)
    unsigned short* buf2   = (unsigned short*)(ws + (5 << 20));   // 10.5 MB (16384*8*40*2)
    float*          part   = (float*)(ws + (5 << 20));            //   8 MB, ALIASES buf2:
    // part is written by tau_p and fully consumed by tau_m BEFORE filter_k writes buf2.

    hipLaunchKernelGGL(split_k,  dim3(1024), dim3(256), 0, stream, x, xh, nrm, eres);
    hipLaunchKernelGGL(red_k,    dim3(2),    dim3(256), 0, stream, nrm, eres, EH);
    hipLaunchKernelGGL(tau_p,    dim3(512),  dim3(256), 0, stream, xh, nrm, part);
    hipLaunchKernelGGL(tau_m,    dim3(256),  dim3(64),  0, stream, part, nrm, eres, EH, tau);
    hipLaunchKernelGGL(filter_k, dim3(512),  dim3(512), 0, stream, xh, nrm, tau, cnt_pb, buf2);
    hipLaunchKernelGGL(rerank_k, dim3(4096), dim3(256), 0, stream, x, cnt_pb, buf2, out);
}